// Round 8
// baseline (2490.896 us; speedup 1.0000x reference)
//
#include <hip/hip_runtime.h>
#include <math.h>

#define Nx   5000
#define Kx   16
#define Hx   128
#define Mx   40000

typedef __attribute__((ext_vector_type(8))) short sh8;   // 8 bf16 (4 VGPR)
typedef __attribute__((ext_vector_type(4))) float f32x4; // MFMA acc

__device__ __forceinline__ float sigf(float v) {
    return __fdividef(1.0f, 1.0f + __expf(-v));
}
__device__ __forceinline__ float tanf_(float v) {
    return 1.0f - __fdividef(2.0f, __expf(2.0f * v) + 1.0f);
}
__device__ __forceinline__ unsigned short rne16(float f) {
    unsigned int u = __float_as_uint(f);
    return (unsigned short)((u + 0x7fffu + ((u >> 16) & 1u)) >> 16);
}
__device__ __forceinline__ float b2f(unsigned short s) {
    return __uint_as_float(((unsigned int)s) << 16);
}

#define FMA4(P, A, Q)                                        \
    P = fmaf((A).x, (Q).x, P); P = fmaf((A).y, (Q).y, P);    \
    P = fmaf((A).z, (Q).z, P); P = fmaf((A).w, (Q).w, P);

#define MFMA3(ACC, XH, XL, WH, WL)                                             \
    ACC = __builtin_amdgcn_mfma_f32_16x16x32_bf16(XH, WH, ACC, 0, 0, 0);       \
    ACC = __builtin_amdgcn_mfma_f32_16x16x32_bf16(XL, WH, ACC, 0, 0, 0);       \
    ACC = __builtin_amdgcn_mfma_f32_16x16x32_bf16(XH, WL, ACC, 0, 0, 0);

// ---------------------------------------------------------------------------
// Kernel P (prep): split x / W_ih / W_hh / W_self into bf16 hi + residual lo.
// W matrices are packed into per-wave MFMA fragments (same pidx as before:
// (gdim,kcol) -> ((dg16*4+kt)*64 + quad*16 + r16)*8 + e). bsum = b_ih + b_hh.
// ---------------------------------------------------------------------------
__global__ __launch_bounds__(256) void kp(const float* __restrict__ x,
        const float* __restrict__ W_ih, const float* __restrict__ W_hh,
        const float* __restrict__ W_self, const float* __restrict__ b_ih,
        const float* __restrict__ b_hh,
        unsigned short* __restrict__ xhi, unsigned short* __restrict__ xlo,
        unsigned short* __restrict__ WIH, unsigned short* __restrict__ WIL,
        unsigned short* __restrict__ WHH, unsigned short* __restrict__ WHL,
        unsigned short* __restrict__ WSH, unsigned short* __restrict__ WSL,
        float* __restrict__ bsum)
{
    const int i = blockIdx.x * 256 + threadIdx.x;
    if (i < Mx * 128) {
        const float v = x[i];
        const unsigned short h = rne16(v);
        xhi[i] = h;
        xlo[i] = rne16(v - b2f(h));
    }
    if (i < 512 * 128) {
        const int gdim = i >> 7, kcol = i & 127;
        const int dg16 = gdim >> 4, r16 = gdim & 15;
        const int kt = kcol >> 5, quad = (kcol >> 3) & 3, e = kcol & 7;
        const int pidx = (((dg16 * 4 + kt) * 64) + quad * 16 + r16) * 8 + e;
        const float wi_ = W_ih[i];
        const unsigned short h1 = rne16(wi_);
        WIH[pidx] = h1; WIL[pidx] = rne16(wi_ - b2f(h1));
        const float wh_ = W_hh[i];
        const unsigned short h2 = rne16(wh_);
        WHH[pidx] = h2; WHL[pidx] = rne16(wh_ - b2f(h2));
        if (i < 128 * 128) {   // dg16 in 0..7
            const float ws_ = W_self[i];
            const unsigned short h3 = rne16(ws_);
            WSH[pidx] = h3; WSL[pidx] = rne16(ws_ - b2f(h3));
        }
        if (i < 512) bsum[i] = b_ih[i] + b_hh[i];
    }
}

// ---------------------------------------------------------------------------
// Kernel F (fused): gathers x (bf16 hi/lo, 512B/row) instead of G (2KB/row).
// Per step: [x-gather issues] [acc=bias] [W_hh 3-split chain from LDS h]
// [W_ih 3-split chain from gathered x, wk-scaled into acc] [activations]
// [hs writeback]. S computed in-prologue via W_self MFMA into LDS.
// 256 thr (4 waves), 32 seqs/block; wave v owns dims v*32..+32 of all gates.
// ---------------------------------------------------------------------------
__global__ __launch_bounds__(256, 2) void kf(
        const unsigned short* __restrict__ xhi, const unsigned short* __restrict__ xlo,
        const unsigned short* __restrict__ WIH, const unsigned short* __restrict__ WIL,
        const unsigned short* __restrict__ WHH, const unsigned short* __restrict__ WHL,
        const unsigned short* __restrict__ WSH, const unsigned short* __restrict__ WSL,
        const float* __restrict__ bsum, const float* __restrict__ b_self,
        const int* __restrict__ nidx, const float* __restrict__ nw,
        const float* __restrict__ W_comb, const float* __restrict__ b_comb,
        float* __restrict__ out)
{
    // [0,8192) hsHI u16[32][128]; [8192,16384) hsLO; [16384,18432) gofs;
    // [18432,20480) wts; [20480,37888) hsS f32[32][136].
    // hsF f32[32][136] aliases [0,17408) (hs + dead gofs half, last step only).
    __shared__ __align__(16) char smem[37888];
    unsigned short* hsHI = (unsigned short*)smem;
    unsigned short* hsLO = (unsigned short*)(smem + 8192);
    float*          hsF  = (float*)smem;
    int*            gofs = (int*)(smem + 16384);
    float*          wts  = (float*)(smem + 18432);
    float*          hsS  = (float*)(smem + 20480);

    const int tid  = threadIdx.x;
    const int lane = tid & 63;
    const int v    = tid >> 6;        // wave 0..3
    const int r16  = lane & 15;
    const int quad = lane >> 4;       // 0..3
    const int kk   = r16 & 7;         // hs-read swizzle key
    const int dimb = v * 32;
    const int m0   = blockIdx.x * 32;

    for (int i = tid; i < 512; i += 256) {
        const int s = i & 31, kstep = i >> 5;
        const int m = m0 + s;
        const int bb = m / Nx;
        const int nn = m - bb * Nx;
        gofs[kstep * 32 + s] = (bb * Nx + nidx[nn * Kx + kstep]) * 128;
        wts [kstep * 32 + s] = nw[nn * Kx + kstep];
    }

    float bsv[4][2];
    #pragma unroll
    for (int g = 0; g < 4; ++g)
        #pragma unroll
        for (int b2 = 0; b2 < 2; ++b2)
            bsv[g][b2] = bsum[g * 128 + dimb + (b2 << 4) + r16];

    // ---- S-part: hsS = x[own rows] @ W_self^T + b_self (3-split MFMA) ----
    {
        f32x4 accs[2][2];
        const float bS0 = b_self[dimb + r16];
        const float bS1 = b_self[dimb + 16 + r16];
        accs[0][0] = (f32x4)bS0; accs[0][1] = (f32x4)bS1;
        accs[1][0] = (f32x4)bS0; accs[1][1] = (f32x4)bS1;
        #pragma unroll
        for (int kt = 0; kt < 4; ++kt) {
            sh8 axh[2], axl[2];
            #pragma unroll
            for (int mt = 0; mt < 2; ++mt) {
                const int xe = (m0 + mt * 16 + r16) * 128 + kt * 32 + quad * 8;
                axh[mt] = *(const sh8*)(xhi + xe);
                axl[mt] = *(const sh8*)(xlo + xe);
            }
            #pragma unroll
            for (int b2 = 0; b2 < 2; ++b2) {
                const int wi = ((v * 2 + b2) * 4 + kt) * 64 + lane;
                const sh8 wh = ((const sh8*)WSH)[wi];
                const sh8 wl = ((const sh8*)WSL)[wi];
                #pragma unroll
                for (int mt = 0; mt < 2; ++mt) { MFMA3(accs[mt][b2], axh[mt], axl[mt], wh, wl); }
            }
        }
        #pragma unroll
        for (int mt = 0; mt < 2; ++mt)
            #pragma unroll
            for (int b2 = 0; b2 < 2; ++b2)
                #pragma unroll
                for (int j = 0; j < 4; ++j)
                    hsS[(mt * 16 + quad * 4 + j) * 136 + dimb + (b2 << 4) + r16]
                        = accs[mt][b2][j];
    }

    float cst[2][2][4];
    #pragma unroll
    for (int mt = 0; mt < 2; ++mt)
        #pragma unroll
        for (int b2 = 0; b2 < 2; ++b2)
            #pragma unroll
            for (int j = 0; j < 4; ++j) cst[mt][b2][j] = 0.f;

    __syncthreads();

    #pragma unroll 1
    for (int k = 0; k < Kx; ++k) {
        // ---- issue x A-frag gathers (consumed after the W_hh chain) ----
        // A-row = r16 -> lane reads ITS seq-row's 64B chunk per kt: sector-perfect.
        sh8 gxh[2][4], gxl[2][4];
        #pragma unroll
        for (int mt = 0; mt < 2; ++mt) {
            const int ro = gofs[k * 32 + mt * 16 + r16];
            #pragma unroll
            for (int kt = 0; kt < 4; ++kt) {
                gxh[mt][kt] = *(const sh8*)(xhi + ro + kt * 32 + quad * 8);
                gxl[mt][kt] = *(const sh8*)(xlo + ro + kt * 32 + quad * 8);
            }
        }
        float wkv[2][4];
        #pragma unroll
        for (int mt = 0; mt < 2; ++mt)
            #pragma unroll
            for (int j = 0; j < 4; ++j)
                wkv[mt][j] = wts[k * 32 + mt * 16 + quad * 4 + j];

        f32x4 acc[2][4][2];
        #pragma unroll
        for (int mt = 0; mt < 2; ++mt)
            #pragma unroll
            for (int g = 0; g < 4; ++g)
                #pragma unroll
                for (int b2 = 0; b2 < 2; ++b2)
                    acc[mt][g][b2] = (f32x4)bsv[g][b2];

        if (k) {  // ---- h @ W_hh^T (h == 0 at k == 0) ----
            #pragma unroll
            for (int kt = 0; kt < 4; ++kt) {
                const int rsw = ((kt << 2) + quad) ^ kk;
                sh8 ahi[2], alo[2];
                #pragma unroll
                for (int mt = 0; mt < 2; ++mt) {
                    const int ro = (mt * 16 + r16) * 16 + rsw;
                    ahi[mt] = ((const sh8*)hsHI)[ro];
                    alo[mt] = ((const sh8*)hsLO)[ro];
                }
                #pragma unroll
                for (int g = 0; g < 4; ++g)
                    #pragma unroll
                    for (int b2 = 0; b2 < 2; ++b2) {
                        const int wi = ((g * 8 + v * 2 + b2) * 4 + kt) * 64 + lane;
                        const sh8 wh = ((const sh8*)WHH)[wi];
                        const sh8 wl = ((const sh8*)WHL)[wi];
                        #pragma unroll
                        for (int mt = 0; mt < 2; ++mt) { MFMA3(acc[mt][g][b2], ahi[mt], alo[mt], wh, wl); }
                    }
            }
        }

        // ---- (w*x) @ W_ih^T: 3-split on gathered x, wk-scaled into acc ----
        #pragma unroll
        for (int gh = 0; gh < 2; ++gh) {
            f32x4 a2[2][2][2];  // [mt][gg][b2]
            #pragma unroll
            for (int mt = 0; mt < 2; ++mt)
                #pragma unroll
                for (int gg = 0; gg < 2; ++gg)
                    #pragma unroll
                    for (int b2 = 0; b2 < 2; ++b2) a2[mt][gg][b2] = (f32x4)0.f;
            #pragma unroll
            for (int kt = 0; kt < 4; ++kt)
                #pragma unroll
                for (int gg = 0; gg < 2; ++gg)
                    #pragma unroll
                    for (int b2 = 0; b2 < 2; ++b2) {
                        const int g = gh * 2 + gg;
                        const int wi = ((g * 8 + v * 2 + b2) * 4 + kt) * 64 + lane;
                        const sh8 wh = ((const sh8*)WIH)[wi];
                        const sh8 wl = ((const sh8*)WIL)[wi];
                        #pragma unroll
                        for (int mt = 0; mt < 2; ++mt) { MFMA3(a2[mt][gg][b2], gxh[mt][kt], gxl[mt][kt], wh, wl); }
                    }
            #pragma unroll
            for (int mt = 0; mt < 2; ++mt)
                #pragma unroll
                for (int gg = 0; gg < 2; ++gg)
                    #pragma unroll
                    for (int b2 = 0; b2 < 2; ++b2)
                        #pragma unroll
                        for (int j = 0; j < 4; ++j)
                            acc[mt][gh * 2 + gg][b2][j] += wkv[mt][j] * a2[mt][gg][b2][j];
        }

        // ---- activations: i,f,g,o -> c,h ----
        float hval[2][2][4];
        #pragma unroll
        for (int mt = 0; mt < 2; ++mt)
            #pragma unroll
            for (int b2 = 0; b2 < 2; ++b2)
                #pragma unroll
                for (int j = 0; j < 4; ++j) {
                    const float ig = sigf(acc[mt][0][b2][j]);
                    const float fg = sigf(acc[mt][1][b2][j]);
                    const float gg = tanf_(acc[mt][2][b2][j]);
                    const float og = sigf(acc[mt][3][b2][j]);
                    const float cc = fg * cst[mt][b2][j] + ig * gg;
                    cst[mt][b2][j] = cc;
                    hval[mt][b2][j] = og * tanf_(cc);
                }

        __syncthreads();  // hs reads of this step done before overwrite

        if (k < Kx - 1) {
            #pragma unroll
            for (int mt = 0; mt < 2; ++mt)
                #pragma unroll
                for (int b2 = 0; b2 < 2; ++b2)
                    #pragma unroll
                    for (int j = 0; j < 4; ++j) {
                        const int seq = mt * 16 + quad * 4 + j;
                        const int dim = dimb + (b2 << 4) + r16;
                        const int idx = (seq << 7) +
                                        ((((dim >> 3) ^ (seq & 7))) << 3) + (dim & 7);
                        const float f = hval[mt][b2][j];
                        const unsigned short hi = rne16(f);
                        hsHI[idx] = hi;
                        hsLO[idx] = rne16(f - b2f(hi));
                    }
        } else {  // final step: park h as f32 (aliases hs + dead gofs half)
            #pragma unroll
            for (int mt = 0; mt < 2; ++mt)
                #pragma unroll
                for (int b2 = 0; b2 < 2; ++b2)
                    #pragma unroll
                    for (int j = 0; j < 4; ++j) {
                        const int seq = mt * 16 + quad * 4 + j;
                        const int dim = dimb + (b2 << 4) + r16;
                        hsF[seq * 136 + dim] = hval[mt][b2][j];
                    }
        }
        __syncthreads();
    }

    // ---- epilogue: out = relu([S, h] @ W_comb^T + b_comb), S from LDS ----
    const int dg = tid & 31;
    const int sg = tid >> 5;
    float ac[4][4];
    #pragma unroll
    for (int i = 0; i < 4; ++i)
        #pragma unroll
        for (int j = 0; j < 4; ++j) ac[i][j] = 0.f;

    const float4* W4 = (const float4*)W_comb;
    #pragma unroll 4
    for (int d4 = 0; d4 < 32; ++d4) {
        float4 sv[4], wv[4];
        #pragma unroll
        for (int i = 0; i < 4; ++i)
            sv[i] = *(const float4*)(hsS + (sg * 4 + i) * 136 + d4 * 4);
        #pragma unroll
        for (int j = 0; j < 4; ++j) wv[j] = W4[(dg * 4 + j) * 64 + d4];
        #pragma unroll
        for (int i = 0; i < 4; ++i) {
            #pragma unroll
            for (int j = 0; j < 4; ++j) { FMA4(ac[i][j], sv[i], wv[j]); }
        }
    }
    #pragma unroll 4
    for (int d4 = 0; d4 < 32; ++d4) {
        float4 hvv[4], wv[4];
        #pragma unroll
        for (int i = 0; i < 4; ++i)
            hvv[i] = *(const float4*)(hsF + (sg * 4 + i) * 136 + d4 * 4);
        #pragma unroll
        for (int j = 0; j < 4; ++j) wv[j] = W4[(dg * 4 + j) * 64 + 32 + d4];
        #pragma unroll
        for (int i = 0; i < 4; ++i) {
            #pragma unroll
            for (int j = 0; j < 4; ++j) { FMA4(ac[i][j], hvv[i], wv[j]); }
        }
    }
    const float4 bc = ((const float4*)b_comb)[dg];
    #pragma unroll
    for (int i = 0; i < 4; ++i) {
        float4 o4;
        o4.x = fmaxf(ac[i][0] + bc.x, 0.f);
        o4.y = fmaxf(ac[i][1] + bc.y, 0.f);
        o4.z = fmaxf(ac[i][2] + bc.z, 0.f);
        o4.w = fmaxf(ac[i][3] + bc.w, 0.f);
        *(float4*)(out + (size_t)(m0 + sg * 4 + i) * 128 + dg * 4) = o4;
    }
}

extern "C" void kernel_launch(void* const* d_in, const int* in_sizes, int n_in,
                              void* d_out, int out_size, void* d_ws, size_t ws_size,
                              hipStream_t stream)
{
    const float* x      = (const float*)d_in[0];
    const int*   nidx   = (const int*)  d_in[1];
    const float* nw     = (const float*)d_in[2];
    const float* W_ih   = (const float*)d_in[3];
    const float* W_hh   = (const float*)d_in[4];
    const float* b_ih   = (const float*)d_in[5];
    const float* b_hh   = (const float*)d_in[6];
    const float* W_self = (const float*)d_in[7];
    const float* b_self = (const float*)d_in[8];
    const float* W_comb = (const float*)d_in[9];
    const float* b_comb = (const float*)d_in[10];
    float* out = (float*)d_out;

    unsigned short* xhi = (unsigned short*)d_ws;        // 5.12M u16 = 10.24 MB
    unsigned short* xlo = xhi + (size_t)Mx * 128;       // 10.24 MB
    unsigned short* WIH = xlo + (size_t)Mx * 128;       // 128 KB
    unsigned short* WIL = WIH + 512 * 128;
    unsigned short* WHH = WIL + 512 * 128;
    unsigned short* WHL = WHH + 512 * 128;
    unsigned short* WSH = WHL + 512 * 128;              // 32 KB
    unsigned short* WSL = WSH + 128 * 128;
    float* bsum = (float*)(WSL + 128 * 128);            // 2 KB

    kp<<<(Mx * 128 + 255) / 256, 256, 0, stream>>>(x, W_ih, W_hh, W_self,
        b_ih, b_hh, xhi, xlo, WIH, WIL, WHH, WHL, WSH, WSL, bsum);
    kf<<<Mx / 32, 256, 0, stream>>>(xhi, xlo, WIH, WIL, WHH, WHL, WSH, WSL,
        bsum, b_self, nidx, nw, W_comb, b_comb, out);
}